// Round 1
// baseline (1940.633 us; speedup 1.0000x reference)
//
#include <hip/hip_runtime.h>
#include <cstdint>

#define RR 8
#define D0 128
#define D1 64
#define D2 32

static __device__ __forceinline__ float relu_f(float x) { return x > 0.f ? x : 0.f; }

// counts[d*R + r] += 1 per edge
__global__ void count_k(const int* __restrict__ dst, const int* __restrict__ et,
                        int* __restrict__ counts, int E) {
  int e = blockIdx.x * 256 + threadIdx.x;
  if (e < E) atomicAdd(&counts[dst[e] * RR + et[e]], 1);
}

__global__ void invc_k(const int* __restrict__ counts, float* __restrict__ invc, int n) {
  int i = blockIdx.x * 256 + threadIdx.x;
  if (i < n) { int c = counts[i]; invc[i] = 1.0f / (float)(c > 1 ? c : 1); }
}

// Y[n,o] = bias[o] + sum_f act(X[n,f]) * W[f,o]   (root/bias term)
template <int FIN, int FOUT, bool RELU>
__global__ void dense_k(const float* __restrict__ X, const float* __restrict__ W,
                        const float* __restrict__ bias, float* __restrict__ Y, int N) {
  int i = blockIdx.x * 256 + threadIdx.x;
  if (i >= N * FOUT) return;
  int n = i / FOUT, o = i - n * FOUT;
  const float* xr = X + (size_t)n * FIN;
  float acc = bias[o];
#pragma unroll 8
  for (int f = 0; f < FIN; ++f) {
    float xv = xr[f];
    if (RELU) xv = relu_f(xv);
    acc = fmaf(xv, W[f * FOUT + o], acc);
  }
  Y[i] = acc;
}

// Y[n, r*FOUT+o] = sum_f act(X[n,f]) * W[r,f,o]  — NT nodes per thread to amortize W loads
template <int FIN, int FOUT, int NT, bool RELU>
__global__ void relgemm_k(const float* __restrict__ X, const float* __restrict__ W,
                          float* __restrict__ Y, int N) {
  const int J = RR * FOUT;
  int i = blockIdx.x * 256 + threadIdx.x;
  int j = i % J;
  int nb = i / J;
  int n0 = nb * NT;
  if (n0 >= N) return;
  int r = j / FOUT, o = j - r * FOUT;
  const float* wr = W + (size_t)r * FIN * FOUT + o;
  const float* xp[NT];
#pragma unroll
  for (int k = 0; k < NT; ++k) {
    int nk = n0 + k; if (nk >= N) nk = N - 1;
    xp[k] = X + (size_t)nk * FIN;
  }
  float acc[NT];
#pragma unroll
  for (int k = 0; k < NT; ++k) acc[k] = 0.f;
#pragma unroll 4
  for (int f = 0; f < FIN; ++f) {
    float wv = wr[(size_t)f * FOUT];
#pragma unroll
    for (int k = 0; k < NT; ++k) {
      float xv = xp[k][f];
      if (RELU) xv = relu_f(xv);
      acc[k] = fmaf(xv, wv, acc[k]);
    }
  }
#pragma unroll
  for (int k = 0; k < NT; ++k)
    if (n0 + k < N) Y[(size_t)(n0 + k) * J + j] = acc[k];
}

// out[d, f] += Y[src, r, f] * invc[d, r]   — one wave covers FOUT lanes (or 2 edges for FOUT=32)
template <int FOUT>
__global__ void scat_k(const int* __restrict__ src, const int* __restrict__ dst,
                       const int* __restrict__ et, const float* __restrict__ Y,
                       const float* __restrict__ invc, float* __restrict__ out, int E) {
  const int SH = (FOUT == 64) ? 6 : 5;
  long long idx = (long long)blockIdx.x * 256 + threadIdx.x;
  int e = (int)(idx >> SH);
  if (e >= E) return;
  int f = (int)idx & (FOUT - 1);
  int s = src[e], d = dst[e], r = et[e];
  float v = Y[((size_t)s * RR + r) * FOUT + f] * invc[d * RR + r];
  atomicAdd(&out[(size_t)d * FOUT + f], v);
}

// Fallback (small ws): per-edge on-the-fly matvec, no Y buffer
template <int FIN, int FOUT, bool RELU>
__global__ void scatfb_k(const int* __restrict__ src, const int* __restrict__ dst,
                         const int* __restrict__ et, const float* __restrict__ X,
                         const float* __restrict__ W, const float* __restrict__ invc,
                         float* __restrict__ out, int E) {
  const int SH = (FOUT == 64) ? 6 : 5;
  long long idx = (long long)blockIdx.x * 256 + threadIdx.x;
  int e = (int)(idx >> SH);
  if (e >= E) return;
  int o = (int)idx & (FOUT - 1);
  int s = src[e], d = dst[e], r = et[e];
  const float* xr = X + (size_t)s * FIN;
  const float* wr = W + (size_t)r * FIN * FOUT + o;
  float acc = 0.f;
#pragma unroll 8
  for (int f = 0; f < FIN; ++f) {
    float xv = xr[f];
    if (RELU) xv = relu_f(xv);
    acc = fmaf(xv, wr[f * FOUT], acc);
  }
  atomicAdd(&out[(size_t)d * FOUT + o], acc * invc[d * RR + r]);
}

__global__ void sigm_k(float* __restrict__ out, int n) {
  int i = blockIdx.x * 256 + threadIdx.x;
  if (i < n) out[i] = 1.0f / (1.0f + __expf(-out[i]));
}

extern "C" void kernel_launch(void* const* d_in, const int* in_sizes, int n_in,
                              void* d_out, int out_size, void* d_ws, size_t ws_size,
                              hipStream_t stream) {
  const int*   edge_index = (const int*)d_in[0];   // [2, E]: src row then dst row
  const int*   et    = (const int*)d_in[1];        // [E]
  const float* emb   = (const float*)d_in[2];      // [N, 128]
  const float* W1    = (const float*)d_in[3];      // [8, 128, 64]
  const float* root1 = (const float*)d_in[4];      // [128, 64]
  const float* b1    = (const float*)d_in[5];      // [64]
  const float* W2    = (const float*)d_in[6];      // [8, 64, 32]
  const float* root2 = (const float*)d_in[7];      // [64, 32]
  const float* b2    = (const float*)d_in[8];      // [32]
  float* out = (float*)d_out;                      // [N, 32]

  const int E = in_sizes[1];
  const int N = in_sizes[2] / D0;
  const int* src  = edge_index;
  const int* dstp = edge_index + E;

  char* ws = (char*)d_ws;
  size_t off = 0;
  auto alloc = [&](size_t bytes) { size_t o = off; off = (off + bytes + 255) & ~(size_t)255; return o; };
  int*   counts = (int*)(ws + alloc((size_t)N * RR * 4));
  float* invc   = (float*)(ws + alloc((size_t)N * RR * 4));
  float* x1     = (float*)(ws + alloc((size_t)N * D1 * 4));   // layer-1 pre-activation
  size_t needY  = (size_t)N * RR * D1 * 4;                    // 204.8 MB; reused as Y2
  bool fast = (off + needY) <= ws_size;
  float* Y = fast ? (float*)(ws + alloc(needY)) : nullptr;

  auto cdiv = [](size_t a, size_t b) { return (unsigned)((a + b - 1) / b); };

  // counts / invc
  hipMemsetAsync(counts, 0, (size_t)N * RR * 4, stream);
  count_k<<<cdiv(E, 256), 256, 0, stream>>>(dstp, et, counts, E);
  invc_k<<<cdiv((size_t)N * RR, 256), 256, 0, stream>>>(counts, invc, N * RR);

  // ---- layer 1: x1 = emb@root1 + b1 + scatter(Y1) ----
  dense_k<D0, D1, false><<<cdiv((size_t)N * D1, 256), 256, 0, stream>>>(emb, root1, b1, x1, N);
  if (fast) {
    relgemm_k<D0, D1, 8, false><<<cdiv(((size_t)(N + 7) / 8) * RR * D1, 256), 256, 0, stream>>>(emb, W1, Y, N);
    scat_k<D1><<<cdiv((size_t)E * D1, 256), 256, 0, stream>>>(src, dstp, et, Y, invc, x1, E);
  } else {
    scatfb_k<D0, D1, false><<<cdiv((size_t)E * D1, 256), 256, 0, stream>>>(src, dstp, et, emb, W1, invc, x1, E);
  }

  // ---- layer 2: out = relu(x1)@root2 + b2 + scatter(Y2); relu folded into reads ----
  dense_k<D1, D2, true><<<cdiv((size_t)N * D2, 256), 256, 0, stream>>>(x1, root2, b2, out, N);
  if (fast) {
    relgemm_k<D1, D2, 8, true><<<cdiv(((size_t)(N + 7) / 8) * RR * D2, 256), 256, 0, stream>>>(x1, W2, Y, N);
    scat_k<D2><<<cdiv((size_t)E * D2, 256), 256, 0, stream>>>(src, dstp, et, Y, invc, out, E);
  } else {
    scatfb_k<D1, D2, true><<<cdiv((size_t)E * D2, 256), 256, 0, stream>>>(src, dstp, et, x1, W2, invc, out, E);
  }

  sigm_k<<<cdiv((size_t)N * D2, 256), 256, 0, stream>>>(out, N * D2);
}

// Round 2
// 809.214 us; speedup vs baseline: 2.3982x; 2.3982x over previous
//
#include <hip/hip_runtime.h>
#include <cstdint>

#define RR 8
#define D0 128
#define D1 64
#define D2 32

typedef unsigned short u16;
typedef short short8 __attribute__((ext_vector_type(8)));
typedef float floatx4 __attribute__((ext_vector_type(4)));

static __device__ __forceinline__ float relu_f(float x) { return x > 0.f ? x : 0.f; }

static __device__ __forceinline__ u16 f2bf(float x) {
  unsigned int u = __float_as_uint(x);
  u += 0x7fffu + ((u >> 16) & 1u);   // round-to-nearest-even
  return (u16)(u >> 16);
}
static __device__ __forceinline__ float bf2f(u16 v) {
  return __uint_as_float(((unsigned int)v) << 16);
}

// ---- counts / inverse counts ----
__global__ void count_k(const int* __restrict__ dst, const int* __restrict__ et,
                        int* __restrict__ counts, int E) {
  int e = blockIdx.x * 256 + threadIdx.x;
  if (e < E) atomicAdd(&counts[dst[e] * RR + et[e]], 1);
}

__global__ void invc_k(const int* __restrict__ counts, float* __restrict__ invc, int n) {
  int i = blockIdx.x * 256 + threadIdx.x;
  if (i < n) { int c = counts[i]; invc[i] = 1.0f / (float)(c > 1 ? c : 1); }
}

// ---- fp32 -> bf16 convert (optionally fused relu), 4 elems/thread ----
template <bool RELU>
__global__ void cvt_k(const float4* __restrict__ X, ushort4* __restrict__ Xb, int n4) {
  int i = blockIdx.x * 256 + threadIdx.x;
  if (i >= n4) return;
  float4 v = X[i];
  if (RELU) { v.x = relu_f(v.x); v.y = relu_f(v.y); v.z = relu_f(v.z); v.w = relu_f(v.w); }
  ushort4 o;
  o.x = f2bf(v.x); o.y = f2bf(v.y); o.z = f2bf(v.z); o.w = f2bf(v.w);
  Xb[i] = o;
}

// ---- pack [W(r,k,o) | root(k,o)] -> BT[c][k] bf16 (col-major over c = r*FOUT+o, then root) ----
__global__ void packBT_k(const float* __restrict__ W, const float* __restrict__ root,
                         u16* __restrict__ BT, int K, int FOUT, int NC, int YC) {
  int i = blockIdx.x * 256 + threadIdx.x;
  if (i >= NC * K) return;
  int c = i / K, k = i - c * K;
  float v;
  if (c < YC) { int r = c / FOUT, o = c - r * FOUT; v = W[((size_t)r * K + k) * FOUT + o]; }
  else        { int o = c - YC; v = root[(size_t)k * (NC - YC) + o]; }
  BT[(size_t)c * K + k] = f2bf(v);
}

// ---- bf16 MFMA GEMM: [N x K] @ [K x NC] -> Y (bf16, cols<YC) + Xroot (fp32 + bias, cols>=YC)
// block = 256 thr (4 waves), tile 64x64, whole K staged in LDS.
template <int K>
__global__ __launch_bounds__(256) void gemm_k(
    const u16* __restrict__ Xb, const u16* __restrict__ BT,
    const float* __restrict__ bias, u16* __restrict__ Y,
    float* __restrict__ Xroot, int N, int NC, int YC) {
  const int KP = K + 8;                  // +16B pad vs bank conflicts
  __shared__ __align__(16) u16 Al[64 * KP];
  __shared__ __align__(16) u16 Bl[64 * KP];
  const int tid = threadIdx.x;
  const int rowBlk = blockIdx.y, colBlk = blockIdx.x;
  const int CH = K / 8;                  // 16B chunks per row

  for (int c = tid; c < 64 * CH; c += 256) {
    int row = c / CH, kc = c - row * CH;
    int gr = rowBlk * 64 + row; if (gr >= N) gr = N - 1;
    *(uint4*)&Al[row * KP + kc * 8] = *(const uint4*)&Xb[(size_t)gr * K + kc * 8];
  }
  for (int c = tid; c < 64 * CH; c += 256) {
    int col = c / CH, kc = c - col * CH;
    int gc = colBlk * 64 + col; if (gc >= NC) gc = NC - 1;
    *(uint4*)&Bl[col * KP + kc * 8] = *(const uint4*)&BT[(size_t)gc * K + kc * 8];
  }
  __syncthreads();

  const int lane = tid & 63, wid = tid >> 6;
  const int l16 = lane & 15, quad = lane >> 4;
  const int wrow = (wid >> 1) * 32, wcol = (wid & 1) * 32;

  floatx4 acc[2][2] = {};
#pragma unroll
  for (int ks = 0; ks < K / 32; ++ks) {
    int ko = ks * 32 + quad * 8;
    short8 a0 = *(const short8*)&Al[(wrow +      l16) * KP + ko];
    short8 a1 = *(const short8*)&Al[(wrow + 16 + l16) * KP + ko];
    short8 b0 = *(const short8*)&Bl[(wcol +      l16) * KP + ko];
    short8 b1 = *(const short8*)&Bl[(wcol + 16 + l16) * KP + ko];
    acc[0][0] = __builtin_amdgcn_mfma_f32_16x16x32_bf16(a0, b0, acc[0][0], 0, 0, 0);
    acc[0][1] = __builtin_amdgcn_mfma_f32_16x16x32_bf16(a0, b1, acc[0][1], 0, 0, 0);
    acc[1][0] = __builtin_amdgcn_mfma_f32_16x16x32_bf16(a1, b0, acc[1][0], 0, 0, 0);
    acc[1][1] = __builtin_amdgcn_mfma_f32_16x16x32_bf16(a1, b1, acc[1][1], 0, 0, 0);
  }

  const int ROOTC = NC - YC;
#pragma unroll
  for (int mi = 0; mi < 2; ++mi)
#pragma unroll
    for (int ni = 0; ni < 2; ++ni)
#pragma unroll
      for (int rg = 0; rg < 4; ++rg) {
        int row = rowBlk * 64 + wrow + mi * 16 + quad * 4 + rg;   // C/D: row = quad*4+reg
        int col = colBlk * 64 + wcol + ni * 16 + l16;             //      col = lane&15
        if (row < N && col < NC) {
          float v = acc[mi][ni][rg];
          if (col < YC) Y[(size_t)row * YC + col] = f2bf(v);
          else          Xroot[(size_t)row * ROOTC + (col - YC)] = v + bias[col - YC];
        }
      }
}

// ---- scatter: out[d,f] += bf2f(Y[s, r*FOUT+f]) * invc[d,r] ----
template <int FOUT>
__global__ void scat_k(const int* __restrict__ src, const int* __restrict__ dst,
                       const int* __restrict__ et, const u16* __restrict__ Y,
                       const float* __restrict__ invc, float* __restrict__ out, int E) {
  const int SH = (FOUT == 64) ? 6 : 5;
  long long idx = (long long)blockIdx.x * 256 + threadIdx.x;
  int e = (int)(idx >> SH);
  if (e >= E) return;
  int f = (int)idx & (FOUT - 1);
  int s = src[e], d = dst[e], r = et[e];
  float v = bf2f(Y[((size_t)s * RR + r) * FOUT + f]) * invc[d * RR + r];
  atomicAdd(&out[(size_t)d * FOUT + f], v);
}

__global__ void sigm_k(float* __restrict__ out, int n) {
  int i = blockIdx.x * 256 + threadIdx.x;
  if (i < n) out[i] = 1.0f / (1.0f + __expf(-out[i]));
}

extern "C" void kernel_launch(void* const* d_in, const int* in_sizes, int n_in,
                              void* d_out, int out_size, void* d_ws, size_t ws_size,
                              hipStream_t stream) {
  const int*   edge_index = (const int*)d_in[0];   // [2, E]
  const int*   et    = (const int*)d_in[1];
  const float* emb   = (const float*)d_in[2];      // [N, 128]
  const float* W1    = (const float*)d_in[3];      // [8, 128, 64]
  const float* root1 = (const float*)d_in[4];      // [128, 64]
  const float* b1    = (const float*)d_in[5];      // [64]
  const float* W2    = (const float*)d_in[6];      // [8, 64, 32]
  const float* root2 = (const float*)d_in[7];      // [64, 32]
  const float* b2    = (const float*)d_in[8];      // [32]
  float* out = (float*)d_out;                      // [N, 32]

  const int E = in_sizes[1];
  const int N = in_sizes[2] / D0;
  const int* src  = edge_index;
  const int* dstp = edge_index + E;

  char* ws = (char*)d_ws;
  size_t off = 0;
  auto alloc = [&](size_t bytes) { size_t o = off; off = (off + bytes + 255) & ~(size_t)255; return o; };
  int*   counts = (int*)(ws + alloc((size_t)N * RR * 4));
  float* invc   = (float*)(ws + alloc((size_t)N * RR * 4));
  float* x1     = (float*)(ws + alloc((size_t)N * D1 * 4));       // layer-1 pre-activation (fp32)
  u16*   Xb     = (u16*)(ws + alloc((size_t)N * D0 * 2));         // emb bf16
  u16*   X1b    = (u16*)(ws + alloc((size_t)N * D1 * 2));         // relu(x1) bf16
  u16*   BT1    = (u16*)(ws + alloc((size_t)(RR * D1 + D1) * D0 * 2));  // [576][128]
  u16*   BT2    = (u16*)(ws + alloc((size_t)(RR * D2 + D2) * D1 * 2));  // [288][64]
  u16*   Y      = (u16*)(ws + alloc((size_t)N * RR * D1 * 2));    // Y1 [N][512] bf16; reused as Y2 [N][256]

  auto cdiv = [](size_t a, size_t b) { return (unsigned)((a + b - 1) / b); };

  const int NC1 = RR * D1 + D1;  // 576
  const int YC1 = RR * D1;       // 512
  const int NC2 = RR * D2 + D2;  // 288
  const int YC2 = RR * D2;       // 256

  // counts / invc
  hipMemsetAsync(counts, 0, (size_t)N * RR * 4, stream);
  count_k<<<cdiv(E, 256), 256, 0, stream>>>(dstp, et, counts, E);
  invc_k<<<cdiv((size_t)N * RR, 256), 256, 0, stream>>>(counts, invc, N * RR);

  // pack inputs to bf16
  cvt_k<false><<<cdiv((size_t)N * D0 / 4, 256), 256, 0, stream>>>((const float4*)emb, (ushort4*)Xb, N * D0 / 4);
  packBT_k<<<cdiv((size_t)NC1 * D0, 256), 256, 0, stream>>>(W1, root1, BT1, D0, D1, NC1, YC1);
  packBT_k<<<cdiv((size_t)NC2 * D1, 256), 256, 0, stream>>>(W2, root2, BT2, D1, D2, NC2, YC2);

  // ---- layer 1 ----
  {
    dim3 grid(cdiv(NC1, 64), cdiv(N, 64));
    gemm_k<D0><<<grid, 256, 0, stream>>>(Xb, BT1, b1, Y, x1, N, NC1, YC1);
  }
  scat_k<D1><<<cdiv((size_t)E * D1, 256), 256, 0, stream>>>(src, dstp, et, Y, invc, x1, E);

  // ---- layer 2 ----
  cvt_k<true><<<cdiv((size_t)N * D1 / 4, 256), 256, 0, stream>>>((const float4*)x1, (ushort4*)X1b, N * D1 / 4);
  {
    dim3 grid(cdiv(NC2, 64), cdiv(N, 64));
    gemm_k<D1><<<grid, 256, 0, stream>>>(X1b, BT2, b2, Y, out, N, NC2, YC2);
  }
  scat_k<D2><<<cdiv((size_t)E * D2, 256), 256, 0, stream>>>(src, dstp, et, Y, invc, out, E);

  sigm_k<<<cdiv((size_t)N * D2, 256), 256, 0, stream>>>(out, N * D2);
}

// Round 3
// 533.114 us; speedup vs baseline: 3.6402x; 1.5179x over previous
//
#include <hip/hip_runtime.h>
#include <cstdint>

#define RR 8
#define D0 128
#define D1 64
#define D2 32

typedef unsigned short u16;
typedef unsigned int u32;
typedef short short8 __attribute__((ext_vector_type(8)));
typedef float floatx4 __attribute__((ext_vector_type(4)));

static __device__ __forceinline__ float relu_f(float x) { return x > 0.f ? x : 0.f; }

static __device__ __forceinline__ u16 f2bf(float x) {
  unsigned int u = __float_as_uint(x);
  u += 0x7fffu + ((u >> 16) & 1u);   // RNE
  return (u16)(u >> 16);
}
static __device__ __forceinline__ float bf2f(u16 v) {
  return __uint_as_float(((unsigned int)v) << 16);
}

// ---- per-(dst,rel) counts ----
__global__ void count_k(const int* __restrict__ dst, const int* __restrict__ et,
                        int* __restrict__ counts, int E) {
  int e = blockIdx.x * 256 + threadIdx.x;
  if (e < E) atomicAdd(&counts[dst[e] * RR + et[e]], 1);
}

// per-d: invc for 8 rels + total degree
__global__ void invc_k(const int* __restrict__ counts, float* __restrict__ invc,
                       int* __restrict__ countd, int N) {
  int d = blockIdx.x * 256 + threadIdx.x;
  if (d >= N) return;
  int tot = 0;
#pragma unroll
  for (int r = 0; r < RR; ++r) {
    int c = counts[d * RR + r];
    tot += c;
    invc[d * RR + r] = 1.0f / (float)(c > 1 ? c : 1);
  }
  countd[d] = tot;
}

// ---- 3-kernel exclusive prefix scan over countd (1024 elems / block) ----
__global__ void scan1_k(const int* __restrict__ v, int* __restrict__ bsum, int n) {
  __shared__ int sd[256];
  int b = blockIdx.x, t = threadIdx.x;
  int base = b * 1024 + t * 4;
  int s = 0;
#pragma unroll
  for (int j = 0; j < 4; ++j) { int i = base + j; if (i < n) s += v[i]; }
  sd[t] = s; __syncthreads();
  for (int st = 128; st > 0; st >>= 1) { if (t < st) sd[t] += sd[t + st]; __syncthreads(); }
  if (t == 0) bsum[b] = sd[0];
}
__global__ void scan2_k(int* __restrict__ bsum, int nb) {
  if (threadIdx.x == 0 && blockIdx.x == 0) {
    int acc = 0;
    for (int i = 0; i < nb; ++i) { int t = bsum[i]; bsum[i] = acc; acc += t; }
  }
}
__global__ void scan3_k(const int* __restrict__ v, const int* __restrict__ bsum,
                        int* __restrict__ off, int n) {
  __shared__ int sd[256];
  int b = blockIdx.x, t = threadIdx.x;
  int base = b * 1024 + t * 4;
  int vals[4]; int s = 0; int loc[4];
#pragma unroll
  for (int j = 0; j < 4; ++j) {
    int i = base + j; int x = (i < n) ? v[i] : 0;
    vals[j] = x; loc[j] = s; s += x;
  }
  sd[t] = s; __syncthreads();
  for (int st = 1; st < 256; st <<= 1) {
    int x = (t >= st) ? sd[t - st] : 0;
    __syncthreads(); sd[t] += x; __syncthreads();
  }
  int texcl = sd[t] - s;
#pragma unroll
  for (int j = 0; j < 4; ++j) {
    int i = base + j;
    if (i < n) {
      off[i] = bsum[b] + texcl + loc[j];
      if (i == n - 1) off[n] = bsum[b] + texcl + loc[j] + vals[j];
    }
  }
}

// ---- counting-sort edges by dst: sorted_sr[p] = src*8 + rel ----
__global__ void permute_k(const int* __restrict__ src, const int* __restrict__ dst,
                          const int* __restrict__ et, const int* __restrict__ off,
                          int* __restrict__ cur, int* __restrict__ sorted_sr, int E) {
  int e = blockIdx.x * 256 + threadIdx.x;
  if (e >= E) return;
  int d = dst[e];
  int p = off[d] + atomicAdd(&cur[d], 1);
  sorted_sr[p] = src[e] * RR + et[e];
}

// ---- fp32 -> bf16 convert ----
__global__ void cvt_k(const float4* __restrict__ X, ushort4* __restrict__ Xb, int n4) {
  int i = blockIdx.x * 256 + threadIdx.x;
  if (i >= n4) return;
  float4 v = X[i];
  ushort4 o; o.x = f2bf(v.x); o.y = f2bf(v.y); o.z = f2bf(v.z); o.w = f2bf(v.w);
  Xb[i] = o;
}

// ---- pack [W(r,k,o) | root(k,o)] -> BT[c][k] bf16 ----
__global__ void packBT_k(const float* __restrict__ W, const float* __restrict__ root,
                         u16* __restrict__ BT, int K, int FOUT, int NC, int YC) {
  int i = blockIdx.x * 256 + threadIdx.x;
  if (i >= NC * K) return;
  int c = i / K, k = i - c * K;
  float v;
  if (c < YC) { int r = c / FOUT, o = c - r * FOUT; v = W[((size_t)r * K + k) * FOUT + o]; }
  else        { int o = c - YC; v = root[(size_t)k * (NC - YC) + o]; }
  BT[(size_t)c * K + k] = f2bf(v);
}

// ---- bf16 MFMA GEMM: tile 64x64, Y bf16 (cols<YC) + Xroot fp32+bias (cols>=YC) ----
template <int K>
__global__ __launch_bounds__(256) void gemm_k(
    const u16* __restrict__ Xb, const u16* __restrict__ BT,
    const float* __restrict__ bias, u16* __restrict__ Y,
    float* __restrict__ Xroot, int N, int NC, int YC) {
  const int KP = K + 8;
  __shared__ __align__(16) u16 Al[64 * KP];
  __shared__ __align__(16) u16 Bl[64 * KP];
  const int tid = threadIdx.x;
  const int rowBlk = blockIdx.y, colBlk = blockIdx.x;
  const int CH = K / 8;

  for (int c = tid; c < 64 * CH; c += 256) {
    int row = c / CH, kc = c - row * CH;
    int gr = rowBlk * 64 + row; if (gr >= N) gr = N - 1;
    *(uint4*)&Al[row * KP + kc * 8] = *(const uint4*)&Xb[(size_t)gr * K + kc * 8];
  }
  for (int c = tid; c < 64 * CH; c += 256) {
    int col = c / CH, kc = c - col * CH;
    int gc = colBlk * 64 + col; if (gc >= NC) gc = NC - 1;
    *(uint4*)&Bl[col * KP + kc * 8] = *(const uint4*)&BT[(size_t)gc * K + kc * 8];
  }
  __syncthreads();

  const int lane = tid & 63, wid = tid >> 6;
  const int l16 = lane & 15, quad = lane >> 4;
  const int wrow = (wid >> 1) * 32, wcol = (wid & 1) * 32;

  floatx4 acc[2][2] = {};
#pragma unroll
  for (int ks = 0; ks < K / 32; ++ks) {
    int ko = ks * 32 + quad * 8;
    short8 a0 = *(const short8*)&Al[(wrow +      l16) * KP + ko];
    short8 a1 = *(const short8*)&Al[(wrow + 16 + l16) * KP + ko];
    short8 b0 = *(const short8*)&Bl[(wcol +      l16) * KP + ko];
    short8 b1 = *(const short8*)&Bl[(wcol + 16 + l16) * KP + ko];
    acc[0][0] = __builtin_amdgcn_mfma_f32_16x16x32_bf16(a0, b0, acc[0][0], 0, 0, 0);
    acc[0][1] = __builtin_amdgcn_mfma_f32_16x16x32_bf16(a0, b1, acc[0][1], 0, 0, 0);
    acc[1][0] = __builtin_amdgcn_mfma_f32_16x16x32_bf16(a1, b0, acc[1][0], 0, 0, 0);
    acc[1][1] = __builtin_amdgcn_mfma_f32_16x16x32_bf16(a1, b1, acc[1][1], 0, 0, 0);
  }

  const int ROOTC = NC - YC;
#pragma unroll
  for (int mi = 0; mi < 2; ++mi)
#pragma unroll
    for (int ni = 0; ni < 2; ++ni)
#pragma unroll
      for (int rg = 0; rg < 4; ++rg) {
        int row = rowBlk * 64 + wrow + mi * 16 + quad * 4 + rg;
        int col = colBlk * 64 + wcol + ni * 16 + l16;
        if (row < N && col < NC) {
          float v = acc[mi][ni][rg];
          if (col < YC) Y[(size_t)row * YC + col] = f2bf(v);
          else          Xroot[(size_t)row * ROOTC + (col - YC)] = v + bias[col - YC];
        }
      }
}

// ---- layer-1 aggregation: one wave per dst, 2 edges/iter, fused root+relu+bf16 ----
__global__ __launch_bounds__(256) void agg1_k(
    const int* __restrict__ off, const int* __restrict__ sorted_sr,
    const u32* __restrict__ Yu, const float* __restrict__ invc,
    const float* __restrict__ xroot, u32* __restrict__ X1b, int N) {
  int d = blockIdx.x * 4 + (threadIdx.x >> 6);
  if (d >= N) return;
  int lane = threadIdx.x & 63;
  int h = lane >> 5, fi = lane & 31;        // edge-half, uint-dim index (2 bf16 dims)
  int beg = off[d], end = off[d + 1];
  float ax = 0.f, ay = 0.f;
  for (int i = beg + h; i < end; i += 2) {
    int sr = sorted_sr[i];
    float w = invc[(d << 3) + (sr & 7)];
    u32 y = Yu[(size_t)sr * 32 + fi];       // Y1: sr*64 bf16 dims = sr*32 uints
    ax = fmaf(bf2f((u16)y), w, ax);
    ay = fmaf(bf2f((u16)(y >> 16)), w, ay);
  }
  ax += __shfl_xor(ax, 32);
  ay += __shfl_xor(ay, 32);
  if (h == 0) {
    float v0 = xroot[(size_t)d * D1 + 2 * fi]     + ax;
    float v1 = xroot[(size_t)d * D1 + 2 * fi + 1] + ay;
    X1b[(size_t)d * 32 + fi] = (u32)f2bf(relu_f(v0)) | ((u32)f2bf(relu_f(v1)) << 16);
  }
}

// ---- layer-2 aggregation: one wave per dst, 4 edges/iter, fused root+sigmoid ----
__global__ __launch_bounds__(256) void agg2_k(
    const int* __restrict__ off, const int* __restrict__ sorted_sr,
    const u32* __restrict__ Yu, const float* __restrict__ invc,
    const float* __restrict__ xroot, float2* __restrict__ out, int N) {
  int d = blockIdx.x * 4 + (threadIdx.x >> 6);
  if (d >= N) return;
  int lane = threadIdx.x & 63;
  int h = lane >> 4, fi = lane & 15;        // edge-quarter, uint-dim index
  int beg = off[d], end = off[d + 1];
  float ax = 0.f, ay = 0.f;
  for (int i = beg + h; i < end; i += 4) {
    int sr = sorted_sr[i];
    float w = invc[(d << 3) + (sr & 7)];
    u32 y = Yu[(size_t)sr * 16 + fi];       // Y2: sr*32 bf16 dims = sr*16 uints
    ax = fmaf(bf2f((u16)y), w, ax);
    ay = fmaf(bf2f((u16)(y >> 16)), w, ay);
  }
  ax += __shfl_xor(ax, 32); ax += __shfl_xor(ax, 16);
  ay += __shfl_xor(ay, 32); ay += __shfl_xor(ay, 16);
  if (h == 0) {
    float v0 = xroot[(size_t)d * D2 + 2 * fi]     + ax;
    float v1 = xroot[(size_t)d * D2 + 2 * fi + 1] + ay;
    float2 o;
    o.x = 1.0f / (1.0f + __expf(-v0));
    o.y = 1.0f / (1.0f + __expf(-v1));
    out[(size_t)d * 16 + fi] = o;
  }
}

extern "C" void kernel_launch(void* const* d_in, const int* in_sizes, int n_in,
                              void* d_out, int out_size, void* d_ws, size_t ws_size,
                              hipStream_t stream) {
  const int*   edge_index = (const int*)d_in[0];
  const int*   et    = (const int*)d_in[1];
  const float* emb   = (const float*)d_in[2];
  const float* W1    = (const float*)d_in[3];
  const float* root1 = (const float*)d_in[4];
  const float* b1    = (const float*)d_in[5];
  const float* W2    = (const float*)d_in[6];
  const float* root2 = (const float*)d_in[7];
  const float* b2    = (const float*)d_in[8];
  float* out = (float*)d_out;

  const int E = in_sizes[1];
  const int N = in_sizes[2] / D0;
  const int* src  = edge_index;
  const int* dstp = edge_index + E;

  char* ws = (char*)d_ws;
  size_t off_b = 0;
  auto alloc = [&](size_t bytes) { size_t o = off_b; off_b = (off_b + bytes + 255) & ~(size_t)255; return o; };
  int*   counts = (int*)(ws + alloc((size_t)N * RR * 4));
  int*   cur    = (int*)(ws + alloc((size_t)N * 4));
  float* invc   = (float*)(ws + alloc((size_t)N * RR * 4));
  int*   countd = (int*)(ws + alloc((size_t)N * 4));
  int*   offs   = (int*)(ws + alloc((size_t)(N + 1) * 4));
  int*   bsum   = (int*)(ws + alloc((size_t)1024 * 4));
  int*   ssr    = (int*)(ws + alloc((size_t)E * 4));             // sorted src*8+rel
  u16*   Xb     = (u16*)(ws + alloc((size_t)N * D0 * 2));
  u16*   X1b    = (u16*)(ws + alloc((size_t)N * D1 * 2));
  float* xr1    = (float*)(ws + alloc((size_t)N * D1 * 4));
  float* xr2    = (float*)(ws + alloc((size_t)N * D2 * 4));
  u16*   BT1    = (u16*)(ws + alloc((size_t)(RR * D1 + D1) * D0 * 2));
  u16*   BT2    = (u16*)(ws + alloc((size_t)(RR * D2 + D2) * D1 * 2));
  u16*   Y      = (u16*)(ws + alloc((size_t)N * RR * D1 * 2));   // Y1; reused as Y2

  auto cdiv = [](size_t a, size_t b) { return (unsigned)((a + b - 1) / b); };

  const int NC1 = RR * D1 + D1, YC1 = RR * D1;  // 576 / 512
  const int NC2 = RR * D2 + D2, YC2 = RR * D2;  // 288 / 256
  const int NB = cdiv(N, 1024);

  // ---- degree counts, invc, CSR offsets, counting sort ----
  hipMemsetAsync(counts, 0, (size_t)N * RR * 4, stream);
  hipMemsetAsync(cur, 0, (size_t)N * 4, stream);
  count_k<<<cdiv(E, 256), 256, 0, stream>>>(dstp, et, counts, E);
  invc_k<<<cdiv(N, 256), 256, 0, stream>>>(counts, invc, countd, N);
  scan1_k<<<NB, 256, 0, stream>>>(countd, bsum, N);
  scan2_k<<<1, 64, 0, stream>>>(bsum, NB);
  scan3_k<<<NB, 256, 0, stream>>>(countd, bsum, offs, N);
  permute_k<<<cdiv(E, 256), 256, 0, stream>>>(src, dstp, et, offs, cur, ssr, E);

  // ---- bf16 packing ----
  cvt_k<<<cdiv((size_t)N * D0 / 4, 256), 256, 0, stream>>>((const float4*)emb, (ushort4*)Xb, N * D0 / 4);
  packBT_k<<<cdiv((size_t)NC1 * D0, 256), 256, 0, stream>>>(W1, root1, BT1, D0, D1, NC1, YC1);
  packBT_k<<<cdiv((size_t)NC2 * D1, 256), 256, 0, stream>>>(W2, root2, BT2, D1, D2, NC2, YC2);

  // ---- layer 1 ----
  {
    dim3 grid(cdiv(NC1, 64), cdiv(N, 64));
    gemm_k<D0><<<grid, 256, 0, stream>>>(Xb, BT1, b1, Y, xr1, N, NC1, YC1);
  }
  agg1_k<<<cdiv(N, 4), 256, 0, stream>>>(offs, ssr, (const u32*)Y, invc, xr1, (u32*)X1b, N);

  // ---- layer 2 ----
  {
    dim3 grid(cdiv(NC2, 64), cdiv(N, 64));
    gemm_k<D1><<<grid, 256, 0, stream>>>(X1b, BT2, b2, Y, xr2, N, NC2, YC2);
  }
  agg2_k<<<cdiv(N, 4), 256, 0, stream>>>(offs, ssr, (const u32*)Y, invc, xr2, (float2*)out, N);
}

// Round 4
// 495.658 us; speedup vs baseline: 3.9153x; 1.0756x over previous
//
#include <hip/hip_runtime.h>
#include <cstdint>

#define RR 8
#define D0 128
#define D1 64
#define D2 32

typedef unsigned short u16;
typedef unsigned int u32;
typedef short short8 __attribute__((ext_vector_type(8)));
typedef float floatx4 __attribute__((ext_vector_type(4)));

static __device__ __forceinline__ float relu_f(float x) { return x > 0.f ? x : 0.f; }

static __device__ __forceinline__ u16 f2bf(float x) {
  unsigned int u = __float_as_uint(x);
  u += 0x7fffu + ((u >> 16) & 1u);   // RNE
  return (u16)(u >> 16);
}
static __device__ __forceinline__ float bf2f(u16 v) {
  return __uint_as_float(((unsigned int)v) << 16);
}

// ---- per-(dst,rel) counts ----
__global__ void count_k(const int* __restrict__ dst, const int* __restrict__ et,
                        int* __restrict__ counts, int E) {
  int e = blockIdx.x * 256 + threadIdx.x;
  if (e < E) atomicAdd(&counts[dst[e] * RR + et[e]], 1);
}

// per-d: invc for 8 rels + total degree
__global__ void invc_k(const int* __restrict__ counts, float* __restrict__ invc,
                       int* __restrict__ countd, int N) {
  int d = blockIdx.x * 256 + threadIdx.x;
  if (d >= N) return;
  int tot = 0;
#pragma unroll
  for (int r = 0; r < RR; ++r) {
    int c = counts[d * RR + r];
    tot += c;
    invc[d * RR + r] = 1.0f / (float)(c > 1 ? c : 1);
  }
  countd[d] = tot;
}

// ---- 3-kernel exclusive prefix scan over countd (1024 elems / block) ----
__global__ void scan1_k(const int* __restrict__ v, int* __restrict__ bsum, int n) {
  __shared__ int sd[256];
  int b = blockIdx.x, t = threadIdx.x;
  int base = b * 1024 + t * 4;
  int s = 0;
#pragma unroll
  for (int j = 0; j < 4; ++j) { int i = base + j; if (i < n) s += v[i]; }
  sd[t] = s; __syncthreads();
  for (int st = 128; st > 0; st >>= 1) { if (t < st) sd[t] += sd[t + st]; __syncthreads(); }
  if (t == 0) bsum[b] = sd[0];
}
__global__ void scan2_k(int* __restrict__ bsum, int nb) {
  if (threadIdx.x == 0 && blockIdx.x == 0) {
    int acc = 0;
    for (int i = 0; i < nb; ++i) { int t = bsum[i]; bsum[i] = acc; acc += t; }
  }
}
__global__ void scan3_k(const int* __restrict__ v, const int* __restrict__ bsum,
                        int* __restrict__ off, int n) {
  __shared__ int sd[256];
  int b = blockIdx.x, t = threadIdx.x;
  int base = b * 1024 + t * 4;
  int vals[4]; int s = 0; int loc[4];
#pragma unroll
  for (int j = 0; j < 4; ++j) {
    int i = base + j; int x = (i < n) ? v[i] : 0;
    vals[j] = x; loc[j] = s; s += x;
  }
  sd[t] = s; __syncthreads();
  for (int st = 1; st < 256; st <<= 1) {
    int x = (t >= st) ? sd[t - st] : 0;
    __syncthreads(); sd[t] += x; __syncthreads();
  }
  int texcl = sd[t] - s;
#pragma unroll
  for (int j = 0; j < 4; ++j) {
    int i = base + j;
    if (i < n) {
      off[i] = bsum[b] + texcl + loc[j];
      if (i == n - 1) off[n] = bsum[b] + texcl + loc[j] + vals[j];
    }
  }
}

// ---- counting-sort edges by dst: sorted_sr[p] = src*8 + rel ----
__global__ void permute_k(const int* __restrict__ src, const int* __restrict__ dst,
                          const int* __restrict__ et, const int* __restrict__ off,
                          int* __restrict__ cur, int* __restrict__ sorted_sr, int E) {
  int e = blockIdx.x * 256 + threadIdx.x;
  if (e >= E) return;
  int d = dst[e];
  int p = off[d] + atomicAdd(&cur[d], 1);
  sorted_sr[p] = src[e] * RR + et[e];
}

// ---- pack [W(r,k,o) | root(k,o)] -> BT[c][k] bf16 ----
__global__ void packBT_k(const float* __restrict__ W, const float* __restrict__ root,
                         u16* __restrict__ BT, int K, int FOUT, int NC, int YC) {
  int i = blockIdx.x * 256 + threadIdx.x;
  if (i >= NC * K) return;
  int c = i / K, k = i - c * K;
  float v;
  if (c < YC) { int r = c / FOUT, o = c - r * FOUT; v = W[((size_t)r * K + k) * FOUT + o]; }
  else        { int o = c - YC; v = root[(size_t)k * (NC - YC) + o]; }
  BT[(size_t)c * K + k] = f2bf(v);
}

// ---- bf16 MFMA GEMM, one 64-row block, internal column-panel loop.
// A staged in LDS once (optionally converted from fp32); B fragments direct from
// global (BT is L2-resident, ~147KB). Y bf16 (cols<YC) + Xroot fp32+bias (cols>=YC).
template <int K, bool AF32>
__global__ __launch_bounds__(256) void gemm_k(
    const void* __restrict__ Aptr, const u16* __restrict__ BT,
    const float* __restrict__ bias, u16* __restrict__ Y,
    float* __restrict__ Xroot, int N, int NC, int YC) {
  const int KP = K + 8;
  __shared__ __align__(16) u16 Al[64 * KP];
  const int tid = threadIdx.x;
  const int rowBlk = blockIdx.x;
  const int CH = K / 8;                       // 8-elem chunks per row

  if (AF32) {
    const float* A = (const float*)Aptr;
    for (int c = tid; c < 64 * CH; c += 256) {
      int row = c / CH, kc = c - row * CH;
      int gr = rowBlk * 64 + row; if (gr >= N) gr = N - 1;
      const float4* p = (const float4*)&A[(size_t)gr * K + kc * 8];
      float4 v0 = p[0], v1 = p[1];
      uint4 o;
      o.x = (u32)f2bf(v0.x) | ((u32)f2bf(v0.y) << 16);
      o.y = (u32)f2bf(v0.z) | ((u32)f2bf(v0.w) << 16);
      o.z = (u32)f2bf(v1.x) | ((u32)f2bf(v1.y) << 16);
      o.w = (u32)f2bf(v1.z) | ((u32)f2bf(v1.w) << 16);
      *(uint4*)&Al[row * KP + kc * 8] = o;
    }
  } else {
    const u16* A = (const u16*)Aptr;
    for (int c = tid; c < 64 * CH; c += 256) {
      int row = c / CH, kc = c - row * CH;
      int gr = rowBlk * 64 + row; if (gr >= N) gr = N - 1;
      *(uint4*)&Al[row * KP + kc * 8] = *(const uint4*)&A[(size_t)gr * K + kc * 8];
    }
  }
  __syncthreads();

  const int lane = tid & 63, wid = tid >> 6;
  const int l16 = lane & 15, quad = lane >> 4;
  const int wrow = (wid >> 1) * 32, wcol = (wid & 1) * 32;
  const int ROOTC = NC - YC;

  for (int cb = 0; cb < NC; cb += 64) {
    int c0 = cb + wcol + l16;      if (c0 >= NC) c0 = NC - 1;
    int c1 = cb + wcol + 16 + l16; if (c1 >= NC) c1 = NC - 1;
    floatx4 acc[2][2] = {};
#pragma unroll
    for (int ks = 0; ks < K / 32; ++ks) {
      int ko = ks * 32 + quad * 8;
      short8 a0 = *(const short8*)&Al[(wrow +      l16) * KP + ko];
      short8 a1 = *(const short8*)&Al[(wrow + 16 + l16) * KP + ko];
      short8 b0 = *(const short8*)&BT[(size_t)c0 * K + ko];
      short8 b1 = *(const short8*)&BT[(size_t)c1 * K + ko];
      acc[0][0] = __builtin_amdgcn_mfma_f32_16x16x32_bf16(a0, b0, acc[0][0], 0, 0, 0);
      acc[0][1] = __builtin_amdgcn_mfma_f32_16x16x32_bf16(a0, b1, acc[0][1], 0, 0, 0);
      acc[1][0] = __builtin_amdgcn_mfma_f32_16x16x32_bf16(a1, b0, acc[1][0], 0, 0, 0);
      acc[1][1] = __builtin_amdgcn_mfma_f32_16x16x32_bf16(a1, b1, acc[1][1], 0, 0, 0);
    }
#pragma unroll
    for (int mi = 0; mi < 2; ++mi)
#pragma unroll
      for (int ni = 0; ni < 2; ++ni)
#pragma unroll
        for (int rg = 0; rg < 4; ++rg) {
          int row = rowBlk * 64 + wrow + mi * 16 + quad * 4 + rg;
          int col = cb + wcol + ni * 16 + l16;
          if (row < N && col < NC) {
            float v = acc[mi][ni][rg];
            if (col < YC) Y[(size_t)row * YC + col] = f2bf(v);
            else          Xroot[(size_t)row * ROOTC + (col - YC)] = v + bias[col - YC];
          }
        }
  }
}

// ---- layer-1 aggregation: one wave per dst, 4 edges/iter x uint2, fused root+relu+bf16 ----
__global__ __launch_bounds__(256) void agg1_k(
    const int* __restrict__ off, const int* __restrict__ ssr,
    const uint2* __restrict__ Yu, const float* __restrict__ invc,
    const float4* __restrict__ xroot, uint2* __restrict__ X1b, int N) {
  int d = blockIdx.x * 4 + (threadIdx.x >> 6);
  if (d >= N) return;
  int lane = threadIdx.x & 63;
  int h = lane >> 4, fi = lane & 15;        // 4 edges in flight, 4 dims/lane
  int beg = off[d], end = off[d + 1];
  float a0 = 0.f, a1 = 0.f, a2 = 0.f, a3 = 0.f;
  for (int i = beg + h; i < end; i += 4) {
    int sr = ssr[i];
    float w = invc[(d << 3) + (sr & 7)];
    uint2 y = Yu[(size_t)sr * 16 + fi];     // Y1 row = 64 bf16 = 16 uint2
    a0 = fmaf(bf2f((u16)y.x), w, a0);
    a1 = fmaf(bf2f((u16)(y.x >> 16)), w, a1);
    a2 = fmaf(bf2f((u16)y.y), w, a2);
    a3 = fmaf(bf2f((u16)(y.y >> 16)), w, a3);
  }
  a0 += __shfl_xor(a0, 32); a0 += __shfl_xor(a0, 16);
  a1 += __shfl_xor(a1, 32); a1 += __shfl_xor(a1, 16);
  a2 += __shfl_xor(a2, 32); a2 += __shfl_xor(a2, 16);
  a3 += __shfl_xor(a3, 32); a3 += __shfl_xor(a3, 16);
  if (h == 0) {
    float4 xr = xroot[(size_t)d * 16 + fi];
    uint2 o;
    o.x = (u32)f2bf(relu_f(xr.x + a0)) | ((u32)f2bf(relu_f(xr.y + a1)) << 16);
    o.y = (u32)f2bf(relu_f(xr.z + a2)) | ((u32)f2bf(relu_f(xr.w + a3)) << 16);
    X1b[(size_t)d * 16 + fi] = o;
  }
}

// ---- layer-2 aggregation: one wave per dst, 8 edges/iter x uint2, fused root+sigmoid ----
__global__ __launch_bounds__(256) void agg2_k(
    const int* __restrict__ off, const int* __restrict__ ssr,
    const uint2* __restrict__ Yu, const float* __restrict__ invc,
    const float4* __restrict__ xroot, float4* __restrict__ out, int N) {
  int d = blockIdx.x * 4 + (threadIdx.x >> 6);
  if (d >= N) return;
  int lane = threadIdx.x & 63;
  int h = lane >> 3, fi = lane & 7;         // 8 edges in flight, 4 dims/lane
  int beg = off[d], end = off[d + 1];
  float a0 = 0.f, a1 = 0.f, a2 = 0.f, a3 = 0.f;
  for (int i = beg + h; i < end; i += 8) {
    int sr = ssr[i];
    float w = invc[(d << 3) + (sr & 7)];
    uint2 y = Yu[(size_t)sr * 8 + fi];      // Y2 row = 32 bf16 = 8 uint2
    a0 = fmaf(bf2f((u16)y.x), w, a0);
    a1 = fmaf(bf2f((u16)(y.x >> 16)), w, a1);
    a2 = fmaf(bf2f((u16)y.y), w, a2);
    a3 = fmaf(bf2f((u16)(y.y >> 16)), w, a3);
  }
  a0 += __shfl_xor(a0, 32); a0 += __shfl_xor(a0, 16); a0 += __shfl_xor(a0, 8);
  a1 += __shfl_xor(a1, 32); a1 += __shfl_xor(a1, 16); a1 += __shfl_xor(a1, 8);
  a2 += __shfl_xor(a2, 32); a2 += __shfl_xor(a2, 16); a2 += __shfl_xor(a2, 8);
  a3 += __shfl_xor(a3, 32); a3 += __shfl_xor(a3, 16); a3 += __shfl_xor(a3, 8);
  if (h == 0) {
    float4 xr = xroot[(size_t)d * 8 + fi];
    float4 o;
    o.x = 1.0f / (1.0f + __expf(-(xr.x + a0)));
    o.y = 1.0f / (1.0f + __expf(-(xr.y + a1)));
    o.z = 1.0f / (1.0f + __expf(-(xr.z + a2)));
    o.w = 1.0f / (1.0f + __expf(-(xr.w + a3)));
    out[(size_t)d * 8 + fi] = o;
  }
}

extern "C" void kernel_launch(void* const* d_in, const int* in_sizes, int n_in,
                              void* d_out, int out_size, void* d_ws, size_t ws_size,
                              hipStream_t stream) {
  const int*   edge_index = (const int*)d_in[0];
  const int*   et    = (const int*)d_in[1];
  const float* emb   = (const float*)d_in[2];
  const float* W1    = (const float*)d_in[3];
  const float* root1 = (const float*)d_in[4];
  const float* b1    = (const float*)d_in[5];
  const float* W2    = (const float*)d_in[6];
  const float* root2 = (const float*)d_in[7];
  const float* b2    = (const float*)d_in[8];
  float* out = (float*)d_out;

  const int E = in_sizes[1];
  const int N = in_sizes[2] / D0;
  const int* src  = edge_index;
  const int* dstp = edge_index + E;

  char* ws = (char*)d_ws;
  size_t off_b = 0;
  auto alloc = [&](size_t bytes) { size_t o = off_b; off_b = (off_b + bytes + 255) & ~(size_t)255; return o; };
  int*   counts = (int*)(ws + alloc((size_t)N * RR * 4));
  int*   cur    = (int*)(ws + alloc((size_t)N * 4));
  float* invc   = (float*)(ws + alloc((size_t)N * RR * 4));
  int*   countd = (int*)(ws + alloc((size_t)N * 4));
  int*   offs   = (int*)(ws + alloc((size_t)(N + 1) * 4));
  int*   bsum   = (int*)(ws + alloc((size_t)1024 * 4));
  int*   ssr    = (int*)(ws + alloc((size_t)E * 4));
  u16*   X1b    = (u16*)(ws + alloc((size_t)N * D1 * 2));
  float* xr1    = (float*)(ws + alloc((size_t)N * D1 * 4));
  float* xr2    = (float*)(ws + alloc((size_t)N * D2 * 4));
  u16*   BT1    = (u16*)(ws + alloc((size_t)(RR * D1 + D1) * D0 * 2));
  u16*   BT2    = (u16*)(ws + alloc((size_t)(RR * D2 + D2) * D1 * 2 + 8192)); // +pad: last-panel clamped reads
  u16*   Y      = (u16*)(ws + alloc((size_t)N * RR * D1 * 2));   // Y1; reused as Y2

  auto cdiv = [](size_t a, size_t b) { return (unsigned)((a + b - 1) / b); };

  const int NC1 = RR * D1 + D1, YC1 = RR * D1;  // 576 / 512
  const int NC2 = RR * D2 + D2, YC2 = RR * D2;  // 288 / 256
  const int NB = cdiv(N, 1024);

  // ---- degree counts, invc, CSR offsets, counting sort ----
  hipMemsetAsync(counts, 0, (size_t)N * RR * 4, stream);
  hipMemsetAsync(cur, 0, (size_t)N * 4, stream);
  count_k<<<cdiv(E, 256), 256, 0, stream>>>(dstp, et, counts, E);
  invc_k<<<cdiv(N, 256), 256, 0, stream>>>(counts, invc, countd, N);
  scan1_k<<<NB, 256, 0, stream>>>(countd, bsum, N);
  scan2_k<<<1, 64, 0, stream>>>(bsum, NB);
  scan3_k<<<NB, 256, 0, stream>>>(countd, bsum, offs, N);
  permute_k<<<cdiv(E, 256), 256, 0, stream>>>(src, dstp, et, offs, cur, ssr, E);

  // ---- weight packing ----
  packBT_k<<<cdiv((size_t)NC1 * D0, 256), 256, 0, stream>>>(W1, root1, BT1, D0, D1, NC1, YC1);
  packBT_k<<<cdiv((size_t)NC2 * D1, 256), 256, 0, stream>>>(W2, root2, BT2, D1, D2, NC2, YC2);

  // ---- layer 1 (A = fp32 emb, convert fused into staging) ----
  gemm_k<D0, true><<<cdiv(N, 64), 256, 0, stream>>>(emb, BT1, b1, Y, xr1, N, NC1, YC1);
  agg1_k<<<cdiv(N, 4), 256, 0, stream>>>(offs, ssr, (const uint2*)Y, invc,
                                         (const float4*)xr1, (uint2*)X1b, N);

  // ---- layer 2 (A = bf16 X1b) ----
  gemm_k<D1, false><<<cdiv(N, 64), 256, 0, stream>>>(X1b, BT2, b2, Y, xr2, N, NC2, YC2);
  agg2_k<<<cdiv(N, 4), 256, 0, stream>>>(offs, ssr, (const uint2*)Y, invc,
                                         (const float4*)xr2, (float4*)out, N);
}